// Round 9
// baseline (321.575 us; speedup 1.0000x reference)
//
#include <hip/hip_runtime.h>

#define N_NODES 50000
#define N_EDGES 800000
#define F 64
#define NROWS (N_NODES * 3)          // 150000 node-(v) rows
#define NPX (N_NODES * 3 * F)        // 9,600,000 floats (px_out size)

typedef float floatx4 __attribute__((ext_vector_type(4)));

__device__ __forceinline__ unsigned short f2bf(float f) {
  unsigned int u = __float_as_uint(f);
  return (unsigned short)((u + 0x7FFFu + ((u >> 16) & 1u)) >> 16);
}
__device__ __forceinline__ float bf2f(unsigned short h) {
  return __uint_as_float(((unsigned int)h) << 16);
}

// --- tiny 64x64 matmul pair: O = A @ B (row-major), one product per block ---
__global__ __launch_bounds__(256) void mm64_pair(
    const float* __restrict__ A0, const float* __restrict__ B0, float* __restrict__ O0,
    const float* __restrict__ A1, const float* __restrict__ B1, float* __restrict__ O1) {
  const float* A = (blockIdx.x == 0) ? A0 : A1;
  const float* B = (blockIdx.x == 0) ? B0 : B1;
  float* O = (blockIdx.x == 0) ? O0 : O1;
  __shared__ float As[64][65];
  __shared__ float Bs[64][65];
  int t = threadIdx.x;
  for (int k = 0; k < 16; ++k) {
    int idx = t + 256 * k;
    As[idx >> 6][idx & 63] = A[idx];
    Bs[idx >> 6][idx & 63] = B[idx];
  }
  __syncthreads();
  int g = t >> 2, f0 = (t & 3) * 16;
  float acc[16];
  #pragma unroll
  for (int j = 0; j < 16; ++j) acc[j] = 0.f;
  for (int k = 0; k < 64; ++k) {
    float a = As[g][k];
    #pragma unroll
    for (int j = 0; j < 16; ++j) acc[j] += a * Bs[k][f0 + j];
  }
  for (int j = 0; j < 16; ++j) O[g * 64 + f0 + j] = acc[j];
}

// --- node GEMM: yi[r,:] = px@Bi^T (f32) ; yjb[r,:] = px@Bj^T (bf16) ---
__global__ __launch_bounds__(256) void node_mm(
    const float* __restrict__ px, const float* __restrict__ Bi,
    const float* __restrict__ Bj, float* __restrict__ yi,
    unsigned short* __restrict__ yjb) {
  __shared__ float pxs[64][68];
  __shared__ float Bs[128][68];    // rows 0..63 = Bi, 64..127 = Bj
  int t = threadIdx.x;
  int r0 = blockIdx.x * 64;
  #pragma unroll
  for (int k = 0; k < 8; ++k) {
    int idx = t + 256 * k;
    int row = idx >> 4, c4 = (idx & 15) * 4;
    const float* src = (row < 64) ? (Bi + row * 64 + c4) : (Bj + (row - 64) * 64 + c4);
    *(float4*)&Bs[row][c4] = *(const float4*)src;
  }
  #pragma unroll
  for (int k = 0; k < 4; ++k) {
    int idx = t + 256 * k;
    int lr = idx >> 4, c4 = (idx & 15) * 4;
    float4 v = make_float4(0.f, 0.f, 0.f, 0.f);
    if (r0 + lr < NROWS) v = *(const float4*)(px + (size_t)(r0 + lr) * 64 + c4);
    *(float4*)&pxs[lr][c4] = v;
  }
  __syncthreads();
  int q = t & 31;
  int rg = t >> 5;
  float acc[8][4];
  #pragma unroll
  for (int r = 0; r < 8; ++r)
    #pragma unroll
    for (int j = 0; j < 4; ++j) acc[r][j] = 0.f;
  #pragma unroll 4
  for (int fc = 0; fc < 16; ++fc) {
    float4 b[4];
    #pragma unroll
    for (int j = 0; j < 4; ++j) b[j] = *(const float4*)&Bs[4 * q + j][fc * 4];
    #pragma unroll
    for (int r = 0; r < 8; ++r) {
      float4 p = *(const float4*)&pxs[rg * 8 + r][fc * 4];
      #pragma unroll
      for (int j = 0; j < 4; ++j)
        acc[r][j] += p.x * b[j].x + p.y * b[j].y + p.z * b[j].z + p.w * b[j].w;
    }
  }
  #pragma unroll
  for (int r = 0; r < 8; ++r) {
    int grow = r0 + rg * 8 + r;
    if (grow >= NROWS) continue;
    if (q < 16) {
      float4 v = make_float4(acc[r][0], acc[r][1], acc[r][2], acc[r][3]);
      *(float4*)(yi + (size_t)grow * 64 + q * 4) = v;
    } else {
      ushort4 h;
      h.x = f2bf(acc[r][0]); h.y = f2bf(acc[r][1]);
      h.z = f2bf(acc[r][2]); h.w = f2bf(acc[r][3]);
      *(ushort4*)(yjb + (size_t)grow * 64 + (q - 16) * 4) = h;
    }
  }
}

// --- CSR build step 1: histogram of idx_i ---
__global__ __launch_bounds__(256) void hist_kernel(
    const int* __restrict__ idx_i, int* __restrict__ cnt) {
  int e = blockIdx.x * 256 + threadIdx.x;
  if (e < N_EDGES) atomicAdd(&cnt[idx_i[e]], 1);
}

// --- CSR build step 2: exclusive scan, 8 elems/thread (single block) ---
__global__ __launch_bounds__(1024) void scan_kernel(
    const int* __restrict__ cnt, int* __restrict__ offs, int* __restrict__ cursor) {
  __shared__ int wsum[16];
  __shared__ int s_carry;
  int t = threadIdx.x, w = t >> 6, l = t & 63;
  if (t == 0) { s_carry = 0; offs[0] = 0; }
  __syncthreads();
  for (int base = 0; base < N_NODES; base += 8192) {
    int i0 = base + t * 8;
    int x[8];
    if (i0 + 7 < N_NODES) {
      int4 a = *(const int4*)(cnt + i0);
      int4 b = *(const int4*)(cnt + i0 + 4);
      x[0] = a.x; x[1] = a.y; x[2] = a.z; x[3] = a.w;
      x[4] = b.x; x[5] = b.y; x[6] = b.z; x[7] = b.w;
    } else {
      #pragma unroll
      for (int k = 0; k < 8; ++k) x[k] = (i0 + k < N_NODES) ? cnt[i0 + k] : 0;
    }
    int incl[8];
    int p = 0;
    #pragma unroll
    for (int k = 0; k < 8; ++k) { p += x[k]; incl[k] = p; }
    int tsum = p;
    int ts = tsum;
    #pragma unroll
    for (int off = 1; off < 64; off <<= 1) {
      int y = __shfl_up(ts, off, 64);
      if (l >= off) ts += y;
    }
    if (l == 63) wsum[w] = ts;
    __syncthreads();
    if (t < 16) {
      int ws_ = wsum[t];
      int si = ws_;
      #pragma unroll
      for (int off = 1; off < 16; off <<= 1) {
        int y = __shfl_up(si, off, 16);
        if (t >= off) si += y;
      }
      wsum[t] = si - ws_;          // exclusive wave base
    }
    __syncthreads();
    int basev = s_carry + wsum[w] + (ts - tsum);
    #pragma unroll
    for (int k = 0; k < 8; ++k) {
      int i = i0 + k;
      if (i < N_NODES) {
        int it = basev + incl[k];
        offs[i + 1] = it;
        cursor[i] = it - x[k];
      }
    }
    __syncthreads();
    if (t == 1023) s_carry = basev + tsum;
    __syncthreads();
  }
}

// --- CSR build step 3: scatter edge id + permuted idx_j + permuted diff ---
__global__ __launch_bounds__(256) void scatter_kernel(
    const int* __restrict__ idx_i, const int* __restrict__ idx_j,
    const float* __restrict__ diff, int* __restrict__ cursor,
    int* __restrict__ perm, int* __restrict__ pnj, float* __restrict__ pdiff) {
  int e = blockIdx.x * 256 + threadIdx.x;
  if (e < N_EDGES) {
    int pos = atomicAdd(&cursor[idx_i[e]], 1);
    perm[pos] = e;
    pnj[pos] = idx_j[e];
    pdiff[pos * 3 + 0] = diff[e * 3 + 0];
    pdiff[pos * 3 + 1] = diff[e * 3 + 1];
    pdiff[pos * 3 + 2] = diff[e * 3 + 2];
  }
}

// --- main: one wave per node; each 16-lane slot owns a WHOLE edge (3 v) ---
// 768B contiguous ix write per edge, 384B contiguous yjb gather per edge.
__global__ __launch_bounds__(64) void node_edge_kernel(
    const int* __restrict__ offs, const int* __restrict__ perm,
    const int* __restrict__ pnj, const float* __restrict__ pdiff,
    const float* __restrict__ yi, const unsigned short* __restrict__ yjb,
    float* __restrict__ ix_out, float* __restrict__ px_out) {
  int n = blockIdx.x;
  int lane = threadIdx.x;            // 0..63
  int s = lane >> 4;                 // edge slot 0..3
  int fqs = (lane & 15) * 4;         // feature quad (element index)
  int start = offs[n], end = offs[n + 1];
  size_t nbase = (size_t)n * 192 + fqs;

  float4 yiv[3];
  #pragma unroll
  for (int v = 0; v < 3; ++v) yiv[v] = *(const float4*)(yi + nbase + v * 64);

  float4 acc[3];
  float sum_d[3];
  #pragma unroll
  for (int v = 0; v < 3; ++v) {
    acc[v] = make_float4(0.f, 0.f, 0.f, 0.f);
    sum_d[v] = 0.f;
  }

  for (int p = start + s; p < end; p += 4) {
    int e  = perm[p];
    int nj = pnj[p];
    float d[3];
    d[0] = pdiff[p * 3 + 0]; d[1] = pdiff[p * 3 + 1]; d[2] = pdiff[p * 3 + 2];
    const unsigned short* ybase = yjb + (size_t)nj * 192 + fqs;
    ushort4 w[3];
    #pragma unroll
    for (int v = 0; v < 3; ++v) w[v] = *(const ushort4*)(ybase + v * 64);
    float* dst = ix_out + (size_t)e * 192 + fqs;
    #pragma unroll
    for (int v = 0; v < 3; ++v) {
      float4 yv = make_float4(bf2f(w[v].x), bf2f(w[v].y), bf2f(w[v].z), bf2f(w[v].w));
      acc[v].x += d[v] * yv.x; acc[v].y += d[v] * yv.y;
      acc[v].z += d[v] * yv.z; acc[v].w += d[v] * yv.w;
      sum_d[v] += d[v];
      floatx4 r;
      r.x = d[v] * (yiv[v].x + yv.x); r.y = d[v] * (yiv[v].y + yv.y);
      r.z = d[v] * (yiv[v].z + yv.z); r.w = d[v] * (yiv[v].w + yv.w);
      __builtin_nontemporal_store(r, (floatx4*)(dst + v * 64));
    }
  }
  // reduce over the 4 edge slots (lanes xor 16, 32)
  #pragma unroll
  for (int mm = 16; mm < 64; mm <<= 1) {
    #pragma unroll
    for (int v = 0; v < 3; ++v) {
      acc[v].x += __shfl_xor(acc[v].x, mm, 64);
      acc[v].y += __shfl_xor(acc[v].y, mm, 64);
      acc[v].z += __shfl_xor(acc[v].z, mm, 64);
      acc[v].w += __shfl_xor(acc[v].w, mm, 64);
      sum_d[v] += __shfl_xor(sum_d[v], mm, 64);
    }
  }
  if (s == 0) {
    #pragma unroll
    for (int v = 0; v < 3; ++v) {
      float4 o = make_float4(yiv[v].x * sum_d[v] + acc[v].x,
                             yiv[v].y * sum_d[v] + acc[v].y,
                             yiv[v].z * sum_d[v] + acc[v].z,
                             yiv[v].w * sum_d[v] + acc[v].w);
      *(float4*)(px_out + nbase + v * 64) = o;
    }
  }
}

extern "C" void kernel_launch(void* const* d_in, const int* in_sizes, int n_in,
                              void* d_out, int out_size, void* d_ws, size_t ws_size,
                              hipStream_t stream) {
  const int*   idx_i = (const int*)d_in[0];
  const int*   idx_j = (const int*)d_in[1];
  const float* px    = (const float*)d_in[2];
  const float* diff  = (const float*)d_in[3];
  const float* W_pp  = (const float*)d_in[4];
  const float* W_i   = (const float*)d_in[5];
  const float* W_j   = (const float*)d_in[6];
  const float* W_ii  = (const float*)d_in[7];

  float* px_out = (float*)d_out;              // [50000,3,64]
  float* ix_out = (float*)d_out + NPX;        // [800000,3,64]

  float* ws = (float*)d_ws;
  float* yi = ws;                              // [150000,64] f32
  unsigned short* yjb = (unsigned short*)(yi + (size_t)NPX);   // [150000,64] bf16
  float* Ci = (float*)(yjb + (size_t)NPX);
  float* Cj = Ci + 4096;
  float* Bi = Cj + 4096;
  float* Bj = Bi + 4096;
  int* cnt    = (int*)(Bj + 4096);             // [50000]
  int* offs   = cnt + N_NODES;                 // [50001]
  int* cursor = offs + N_NODES + 1;            // [50000]
  int* perm   = cursor + N_NODES;              // [800000]
  int* pnj    = perm + N_EDGES;                // [800000]
  float* pdiff = (float*)(pnj + N_EDGES);      // [800000*3]

  (void)hipMemsetAsync(cnt, 0, N_NODES * sizeof(int), stream);

  // Bi = W_ii @ W_i @ W_pp ; Bj = W_ii @ W_j @ W_pp
  mm64_pair<<<2, 256, 0, stream>>>(W_ii, W_i, Ci, W_ii, W_j, Cj);
  mm64_pair<<<2, 256, 0, stream>>>(Ci, W_pp, Bi, Cj, W_pp, Bj);

  node_mm<<<(NROWS + 63) / 64, 256, 0, stream>>>(px, Bi, Bj, yi, yjb);

  hist_kernel<<<(N_EDGES + 255) / 256, 256, 0, stream>>>(idx_i, cnt);
  scan_kernel<<<1, 1024, 0, stream>>>(cnt, offs, cursor);
  scatter_kernel<<<(N_EDGES + 255) / 256, 256, 0, stream>>>(
      idx_i, idx_j, diff, cursor, perm, pnj, pdiff);

  node_edge_kernel<<<N_NODES, 64, 0, stream>>>(offs, perm, pnj, pdiff,
                                               yi, yjb, ix_out, px_out);
}

// Round 10
// 309.477 us; speedup vs baseline: 1.0391x; 1.0391x over previous
//
#include <hip/hip_runtime.h>

#define N_NODES 50000
#define N_EDGES 800000
#define F 64
#define NROWS (N_NODES * 3)          // 150000 node-(v) rows
#define NPX (N_NODES * 3 * F)        // 9,600,000 elems (px_out size)
#define NMM_BLOCKS ((NROWS + 63) / 64)          // 2344
#define HIST_BLOCKS ((N_EDGES + 1023) / 1024)   // 782

typedef float floatx4 __attribute__((ext_vector_type(4)));

__device__ __forceinline__ unsigned short f2bf(float f) {
  unsigned int u = __float_as_uint(f);
  return (unsigned short)((u + 0x7FFFu + ((u >> 16) & 1u)) >> 16);
}
__device__ __forceinline__ float bf2f(unsigned short h) {
  return __uint_as_float(((unsigned int)h) << 16);
}

// --- K1: blocks 0,1 = chained 64x64 matmul (W_ii@Wx)@W_pp ; rest = histogram ---
__global__ __launch_bounds__(256) void pre_kernel(
    const float* __restrict__ W_ii, const float* __restrict__ W_i,
    const float* __restrict__ W_j, const float* __restrict__ W_pp,
    float* __restrict__ Bi, float* __restrict__ Bj,
    const int* __restrict__ idx_i, int* __restrict__ cnt) {
  __shared__ float As[64][65];
  __shared__ float Bs[64][65];
  __shared__ float Ps[64][65];
  if (blockIdx.x >= 2) {
    int b = blockIdx.x - 2;
    int base = b * 1024 + threadIdx.x;
    #pragma unroll
    for (int k = 0; k < 4; ++k) {
      int e = base + k * 256;
      if (e < N_EDGES) atomicAdd(&cnt[idx_i[e]], 1);
    }
    return;
  }
  const float* Wx = (blockIdx.x == 0) ? W_i : W_j;
  float* Out = (blockIdx.x == 0) ? Bi : Bj;
  int t = threadIdx.x;
  for (int k = 0; k < 16; ++k) {
    int idx = t + 256 * k;
    As[idx >> 6][idx & 63] = W_ii[idx];
    Bs[idx >> 6][idx & 63] = Wx[idx];
    Ps[idx >> 6][idx & 63] = W_pp[idx];
  }
  __syncthreads();
  int g = t >> 2, f0 = (t & 3) * 16;
  float acc[16];
  #pragma unroll
  for (int j = 0; j < 16; ++j) acc[j] = 0.f;
  for (int k = 0; k < 64; ++k) {
    float a = As[g][k];
    #pragma unroll
    for (int j = 0; j < 16; ++j) acc[j] += a * Bs[k][f0 + j];
  }
  __syncthreads();
  #pragma unroll
  for (int j = 0; j < 16; ++j) As[g][f0 + j] = acc[j];   // As = W_ii @ Wx
  __syncthreads();
  #pragma unroll
  for (int j = 0; j < 16; ++j) acc[j] = 0.f;
  for (int k = 0; k < 64; ++k) {
    float a = As[g][k];
    #pragma unroll
    for (int j = 0; j < 16; ++j) acc[j] += a * Ps[k][f0 + j];
  }
  for (int j = 0; j < 16; ++j) Out[g * 64 + f0 + j] = acc[j];
}

// --- K2: block 0 = exclusive scan (256 thr, 8/thr) ; blocks 1.. = node GEMM ---
// ybi[r,:] = px@Bi^T (bf16) ; ybj[r,:] = px@Bj^T (bf16)
__global__ __launch_bounds__(256) void mm_scan_kernel(
    const float* __restrict__ px, const float* __restrict__ Bi,
    const float* __restrict__ Bj, unsigned short* __restrict__ ybi,
    unsigned short* __restrict__ ybj,
    const int* __restrict__ cnt, int* __restrict__ offs,
    int* __restrict__ cursor) {
  __shared__ float pxs[64][68];
  __shared__ float Bs[128][68];    // rows 0..63 = Bi, 64..127 = Bj
  __shared__ int wsum[4];
  __shared__ int s_carry;
  int t = threadIdx.x;
  if (blockIdx.x == 0) {
    // exclusive scan of cnt -> offs[1..], cursor (25 chunks of 2048)
    int w = t >> 6, l = t & 63;
    if (t == 0) { s_carry = 0; offs[0] = 0; }
    __syncthreads();
    for (int base = 0; base < N_NODES; base += 2048) {
      int i0 = base + t * 8;
      int x[8];
      if (i0 + 7 < N_NODES) {
        int4 a = *(const int4*)(cnt + i0);
        int4 b = *(const int4*)(cnt + i0 + 4);
        x[0] = a.x; x[1] = a.y; x[2] = a.z; x[3] = a.w;
        x[4] = b.x; x[5] = b.y; x[6] = b.z; x[7] = b.w;
      } else {
        #pragma unroll
        for (int k = 0; k < 8; ++k) x[k] = (i0 + k < N_NODES) ? cnt[i0 + k] : 0;
      }
      int incl[8];
      int p = 0;
      #pragma unroll
      for (int k = 0; k < 8; ++k) { p += x[k]; incl[k] = p; }
      int tsum = p;
      int ts = tsum;
      #pragma unroll
      for (int off = 1; off < 64; off <<= 1) {
        int y = __shfl_up(ts, off, 64);
        if (l >= off) ts += y;
      }
      if (l == 63) wsum[w] = ts;
      __syncthreads();
      if (t == 0) {
        int a = 0;
        #pragma unroll
        for (int k = 0; k < 4; ++k) { int tmp = wsum[k]; wsum[k] = a; a += tmp; }
      }
      __syncthreads();
      int basev = s_carry + wsum[w] + (ts - tsum);
      #pragma unroll
      for (int k = 0; k < 8; ++k) {
        int i = i0 + k;
        if (i < N_NODES) {
          int it = basev + incl[k];
          offs[i + 1] = it;
          cursor[i] = it - x[k];
        }
      }
      __syncthreads();
      if (t == 255) s_carry = basev + tsum;
      __syncthreads();
    }
    return;
  }
  int r0 = (blockIdx.x - 1) * 64;
  #pragma unroll
  for (int k = 0; k < 8; ++k) {
    int idx = t + 256 * k;
    int row = idx >> 4, c4 = (idx & 15) * 4;
    const float* src = (row < 64) ? (Bi + row * 64 + c4) : (Bj + (row - 64) * 64 + c4);
    *(float4*)&Bs[row][c4] = *(const float4*)src;
  }
  #pragma unroll
  for (int k = 0; k < 4; ++k) {
    int idx = t + 256 * k;
    int lr = idx >> 4, c4 = (idx & 15) * 4;
    float4 v = make_float4(0.f, 0.f, 0.f, 0.f);
    if (r0 + lr < NROWS) v = *(const float4*)(px + (size_t)(r0 + lr) * 64 + c4);
    *(float4*)&pxs[lr][c4] = v;
  }
  __syncthreads();
  int q = t & 31;
  int rg = t >> 5;
  float acc[8][4];
  #pragma unroll
  for (int r = 0; r < 8; ++r)
    #pragma unroll
    for (int j = 0; j < 4; ++j) acc[r][j] = 0.f;
  #pragma unroll 4
  for (int fc = 0; fc < 16; ++fc) {
    float4 b[4];
    #pragma unroll
    for (int j = 0; j < 4; ++j) b[j] = *(const float4*)&Bs[4 * q + j][fc * 4];
    #pragma unroll
    for (int r = 0; r < 8; ++r) {
      float4 p = *(const float4*)&pxs[rg * 8 + r][fc * 4];
      #pragma unroll
      for (int j = 0; j < 4; ++j)
        acc[r][j] += p.x * b[j].x + p.y * b[j].y + p.z * b[j].z + p.w * b[j].w;
    }
  }
  #pragma unroll
  for (int r = 0; r < 8; ++r) {
    int grow = r0 + rg * 8 + r;
    if (grow >= NROWS) continue;
    ushort4 h;
    h.x = f2bf(acc[r][0]); h.y = f2bf(acc[r][1]);
    h.z = f2bf(acc[r][2]); h.w = f2bf(acc[r][3]);
    if (q < 16) *(ushort4*)(ybi + (size_t)grow * 64 + q * 4) = h;
    else        *(ushort4*)(ybj + (size_t)grow * 64 + (q - 16) * 4) = h;
  }
}

// --- K3: scatter edge id + permuted idx_j + permuted diff into CSR order ---
__global__ __launch_bounds__(256) void scatter_kernel(
    const int* __restrict__ idx_i, const int* __restrict__ idx_j,
    const float* __restrict__ diff, int* __restrict__ cursor,
    int* __restrict__ perm, int* __restrict__ pnj, float* __restrict__ pdiff) {
  int e = blockIdx.x * 256 + threadIdx.x;
  if (e < N_EDGES) {
    int pos = atomicAdd(&cursor[idx_i[e]], 1);
    perm[pos] = e;
    pnj[pos] = idx_j[e];
    pdiff[pos * 3 + 0] = diff[e * 3 + 0];
    pdiff[pos * 3 + 1] = diff[e * 3 + 1];
    pdiff[pos * 3 + 2] = diff[e * 3 + 2];
  }
}

// --- K4: one wave per node; each 16-lane slot owns a whole edge (3 v) ---
// 768B contiguous ix write per edge, 384B contiguous ybj gather per edge.
__global__ __launch_bounds__(64) void node_edge_kernel(
    const int* __restrict__ offs, const int* __restrict__ perm,
    const int* __restrict__ pnj, const float* __restrict__ pdiff,
    const unsigned short* __restrict__ ybi, const unsigned short* __restrict__ ybj,
    float* __restrict__ ix_out, float* __restrict__ px_out) {
  int n = blockIdx.x;
  int lane = threadIdx.x;            // 0..63
  int s = lane >> 4;                 // edge slot 0..3
  int fqs = (lane & 15) * 4;         // feature quad (element index)
  int start = offs[n], end = offs[n + 1];
  size_t nbase = (size_t)n * 192 + fqs;

  float4 yiv[3];
  #pragma unroll
  for (int v = 0; v < 3; ++v) {
    ushort4 h = *(const ushort4*)(ybi + nbase + v * 64);
    yiv[v] = make_float4(bf2f(h.x), bf2f(h.y), bf2f(h.z), bf2f(h.w));
  }

  float4 acc[3];
  float sum_d[3];
  #pragma unroll
  for (int v = 0; v < 3; ++v) {
    acc[v] = make_float4(0.f, 0.f, 0.f, 0.f);
    sum_d[v] = 0.f;
  }

  for (int p = start + s; p < end; p += 4) {
    int e  = perm[p];
    int nj = pnj[p];
    float d[3];
    d[0] = pdiff[p * 3 + 0]; d[1] = pdiff[p * 3 + 1]; d[2] = pdiff[p * 3 + 2];
    const unsigned short* ybase = ybj + (size_t)nj * 192 + fqs;
    ushort4 w[3];
    #pragma unroll
    for (int v = 0; v < 3; ++v) w[v] = *(const ushort4*)(ybase + v * 64);
    float* dst = ix_out + (size_t)e * 192 + fqs;
    #pragma unroll
    for (int v = 0; v < 3; ++v) {
      float4 yv = make_float4(bf2f(w[v].x), bf2f(w[v].y), bf2f(w[v].z), bf2f(w[v].w));
      acc[v].x += d[v] * yv.x; acc[v].y += d[v] * yv.y;
      acc[v].z += d[v] * yv.z; acc[v].w += d[v] * yv.w;
      sum_d[v] += d[v];
      floatx4 r;
      r.x = d[v] * (yiv[v].x + yv.x); r.y = d[v] * (yiv[v].y + yv.y);
      r.z = d[v] * (yiv[v].z + yv.z); r.w = d[v] * (yiv[v].w + yv.w);
      __builtin_nontemporal_store(r, (floatx4*)(dst + v * 64));
    }
  }
  // reduce over the 4 edge slots (lanes xor 16, 32)
  #pragma unroll
  for (int mm = 16; mm < 64; mm <<= 1) {
    #pragma unroll
    for (int v = 0; v < 3; ++v) {
      acc[v].x += __shfl_xor(acc[v].x, mm, 64);
      acc[v].y += __shfl_xor(acc[v].y, mm, 64);
      acc[v].z += __shfl_xor(acc[v].z, mm, 64);
      acc[v].w += __shfl_xor(acc[v].w, mm, 64);
      sum_d[v] += __shfl_xor(sum_d[v], mm, 64);
    }
  }
  if (s == 0) {
    #pragma unroll
    for (int v = 0; v < 3; ++v) {
      float4 o = make_float4(yiv[v].x * sum_d[v] + acc[v].x,
                             yiv[v].y * sum_d[v] + acc[v].y,
                             yiv[v].z * sum_d[v] + acc[v].z,
                             yiv[v].w * sum_d[v] + acc[v].w);
      *(float4*)(px_out + nbase + v * 64) = o;
    }
  }
}

extern "C" void kernel_launch(void* const* d_in, const int* in_sizes, int n_in,
                              void* d_out, int out_size, void* d_ws, size_t ws_size,
                              hipStream_t stream) {
  const int*   idx_i = (const int*)d_in[0];
  const int*   idx_j = (const int*)d_in[1];
  const float* px    = (const float*)d_in[2];
  const float* diff  = (const float*)d_in[3];
  const float* W_pp  = (const float*)d_in[4];
  const float* W_i   = (const float*)d_in[5];
  const float* W_j   = (const float*)d_in[6];
  const float* W_ii  = (const float*)d_in[7];

  float* px_out = (float*)d_out;              // [50000,3,64]
  float* ix_out = (float*)d_out + NPX;        // [800000,3,64]

  unsigned short* ybi = (unsigned short*)d_ws;             // [150000,64] bf16
  unsigned short* ybj = ybi + (size_t)NPX;                 // [150000,64] bf16
  float* Bi = (float*)(ybj + (size_t)NPX);
  float* Bj = Bi + 4096;
  int* cnt    = (int*)(Bj + 4096);             // [50000]
  int* offs   = cnt + N_NODES;                 // [50001]
  int* cursor = offs + N_NODES + 1;            // [50000]
  int* perm   = cursor + N_NODES;              // [800000]
  int* pnj    = perm + N_EDGES;                // [800000]
  float* pdiff = (float*)(pnj + N_EDGES);      // [800000*3]

  (void)hipMemsetAsync(cnt, 0, N_NODES * sizeof(int), stream);

  // K1: Bi = W_ii@W_i@W_pp, Bj = W_ii@W_j@W_pp (blocks 0,1) || hist (rest)
  pre_kernel<<<2 + HIST_BLOCKS, 256, 0, stream>>>(
      W_ii, W_i, W_j, W_pp, Bi, Bj, idx_i, cnt);

  // K2: scan (block 0) || node GEMM -> bf16 tables (blocks 1..)
  mm_scan_kernel<<<1 + NMM_BLOCKS, 256, 0, stream>>>(
      px, Bi, Bj, ybi, ybj, cnt, offs, cursor);

  scatter_kernel<<<(N_EDGES + 255) / 256, 256, 0, stream>>>(
      idx_i, idx_j, diff, cursor, perm, pnj, pdiff);

  node_edge_kernel<<<N_NODES, 64, 0, stream>>>(offs, perm, pnj, pdiff,
                                               ybi, ybj, ix_out, px_out);
}